// Round 17
// baseline (26.493 us; speedup 1.0000x reference)
//
#include <hip/hip_runtime.h>
#include <stdint.h>

#define N_DIM 256
#define C_DIM 64
#define D_DIM 4096
#define NWAVE 16              // waves per block (K-split ways, in-block)
#define KWV   (D_DIM / NWAVE) // 256 k per wave
#define NSTEP (KWV / 16)      // 16 MFMA k-steps per wave
#define PDEP  5               // u prefetch pipeline depth

// ws layout: uh (f16 u, 512 KB) @0; vh (f16 v, 2 MB) @1MB
#define VH_OFF   (1u << 20)

typedef __bf16    bf16x8_t __attribute__((ext_vector_type(8)));
typedef _Float16  f16x8_t  __attribute__((ext_vector_type(8)));
typedef float     f32x16_t __attribute__((ext_vector_type(16)));
typedef unsigned int u32x4_t __attribute__((ext_vector_type(4)));  // plain vec for nt builtins

union Frag {
  uint4     q;
  uint32_t  u[4];
  bf16x8_t  b;
};
union FragH {
  uint4     q;
  u32x4_t   q4;       // nt-load target (plain ext_vector, builtin-compatible)
  _Float16  h[8];
  f16x8_t   v;
};

__device__ __forceinline__ uint32_t pk_bf16(float lo, float hi) {
  uint32_t d;
  asm("v_cvt_pk_bf16_f32 %0, %1, %2" : "=v"(d) : "v"(lo), "v"(hi));
  return d;
}

#define MFMA32H(a, b, c) __builtin_amdgcn_mfma_f32_32x32x16_f16(a, b, c, 0, 0, 0)
#define MFMA32B(a, b, c) __builtin_amdgcn_mfma_f32_32x32x16_bf16(a, b, c, 0, 0, 0)

// ---- prep helpers (R6/R8-validated) ---------------------------------------
__device__ __forceinline__ void prep_u_unit(const float* __restrict__ u,
                                            _Float16* __restrict__ uh, int t) {
  const int row = t >> 9;
  const int k8  = t & 511;
  const float4* p = (const float4*)(u + (size_t)row * D_DIM + (size_t)k8 * 8);
  const float4 a = p[0], b = p[1];
  FragH o;
  o.h[0] = (_Float16)a.x; o.h[1] = (_Float16)a.y;
  o.h[2] = (_Float16)a.z; o.h[3] = (_Float16)a.w;
  o.h[4] = (_Float16)b.x; o.h[5] = (_Float16)b.y;
  o.h[6] = (_Float16)b.z; o.h[7] = (_Float16)b.w;
  *(uint4*)(uh + (size_t)(k8 * C_DIM + row) * 8) = o.q;
}

__device__ __forceinline__ void prep_v_unit(const float* __restrict__ v,
                                            _Float16* __restrict__ vh, int t) {
  const float4* p = (const float4*)(v + (size_t)t * 8);
  const float4 a = p[0], b = p[1];
  FragH o;
  o.h[0] = (_Float16)a.x; o.h[1] = (_Float16)a.y;
  o.h[2] = (_Float16)a.z; o.h[3] = (_Float16)a.w;
  o.h[4] = (_Float16)b.x; o.h[5] = (_Float16)b.y;
  o.h[6] = (_Float16)b.z; o.h[7] = (_Float16)b.w;
  *(uint4*)(vh + (size_t)t * 8) = o.q;
}

__global__ __launch_bounds__(256) void prep_kernel(const float* __restrict__ u,
                                                   const float* __restrict__ v,
                                                   _Float16* __restrict__ uh,
                                                   _Float16* __restrict__ vh) {
  const int gid = blockIdx.x * 256 + threadIdx.x;
  if (blockIdx.x < 128) prep_u_unit(u, uh, gid);
  else                  prep_v_unit(v, vh, gid - 32768);
}

// ---- gram: one 1024-thread block per n; 16-way K-split; symmetric 3-tile --
// R12-validated loop + NON-TEMPORAL u loads (pure L1-stream, zero reuse).
__global__ __launch_bounds__(1024, 4)
void gram_kernel(const _Float16* __restrict__ vh,
                 const _Float16* __restrict__ uh,
                 float* __restrict__ out)
{
  __shared__ float Red[NWAVE][C_DIM][17];   // 69.6 KB; odd stride -> 2/bank (free)

  const int tid = threadIdx.x;
  const int w   = tid >> 6;      // wave id = K-segment (0..15)
  const int l   = tid & 63;
  const int n   = blockIdx.x;
  const int hg  = l >> 5;
  const int lm  = l & 31;

  f32x16_t acc0, acc1, acc2;     // tiles (0,0), (1,0), (1,1); (0,1)=T(1,0)
#pragma unroll
  for (int i = 0; i < 16; ++i) { acc0[i] = 0.0f; acc1[i] = 0.0f; acc2[i] = 0.0f; }

  // v: f16-packed broadcast loads (validated), wave's 512 B slice (L1-reused)
  const char* vg = (const char*)(vh + (size_t)n * D_DIM + w * KWV) + hg * 16;
  // u fragments: validated subtile addressing; k8 base = w*32 + hg
  const char* up = (const char*)uh + ((size_t)(w * 32 + hg)) * 1024 + (size_t)lm * 16;

  // PDEP-deep u pipeline; nt loads (streaming, no L1 insertion)
  FragH pa[PDEP], pb[PDEP];
#pragma unroll
  for (int i = 0; i < PDEP; ++i) {
    pa[i].q4 = __builtin_nontemporal_load((const u32x4_t*)(up + i * 2048));
    pb[i].q4 = __builtin_nontemporal_load((const u32x4_t*)(up + i * 2048 + 512));
  }
  up += PDEP * 2048;
  uint4 vcur = *(const uint4*)(vg);
  uint4 vnxt = *(const uint4*)(vg + 32);

#pragma unroll
  for (int s = 0; s < NSTEP; ++s) {
    const int cur = s % PDEP;
    FragH vv;
    vv.q = vcur;
    FragH sa0, sa1;
    sa0.v = pa[cur].v * vv.v;     // v_pk_mul_f16
    sa1.v = pb[cur].v * vv.v;
    acc0 = MFMA32H(sa0.v, pa[cur].v, acc0);   // tile (0,0)
    acc1 = MFMA32H(sa1.v, pa[cur].v, acc1);   // tile (1,0)
    acc2 = MFMA32H(sa1.v, pb[cur].v, acc2);   // tile (1,1)
    if (s + PDEP < NSTEP) {       // guarded refill: no tail over-read
      pa[cur].q4 = __builtin_nontemporal_load((const u32x4_t*)(up));
      pb[cur].q4 = __builtin_nontemporal_load((const u32x4_t*)(up + 512));
      up += 2048;
    }
    vcur = vnxt;
    if (s + 2 < NSTEP)
      vnxt = *(const uint4*)(vg + (s + 2) * 32);
  }

  // ---- in-block K-reduction (16 partials) + direct out, 3 phases ----------
  // Producer (validated): acc tile (tr,tc) reg j of lane (hg,lm) ->
  //   row = tr*32 + 4*hg + (j&3) + 8*(j>>2), col = tc*32 + lm.
  // Reader (w,l) owns j = w; sums 16 waves. Phase 1 also stores the
  // transposed element into tile (0,1) (gram is symmetric).
  float* onb = out + (size_t)n * 4096;
#pragma unroll
  for (int p = 0; p < 3; ++p) {
    const int tr = (p >= 1) ? 1 : 0;
    const int tc = (p == 2) ? 1 : 0;
    __syncthreads();                 // Red free for reuse
    {
      const f32x16_t A = (p == 0) ? acc0 : (p == 1) ? acc1 : acc2;
      float* rp = &Red[w][l][0];
#pragma unroll
      for (int j = 0; j < 16; ++j)
        rp[j] = A[j];
    }
    __syncthreads();                 // all partials visible
    {
      float s = 0.0f;
#pragma unroll
      for (int ww = 0; ww < NWAVE; ++ww)
        s += Red[ww][l][w];
      const int row = tr * 32 + 4 * hg + (w & 3) + 8 * (w >> 2);
      const int col = tc * 32 + lm;
      onb[(size_t)row * 64 + col] = s;
      if (p == 1)                    // mirror into tile (0,1)
        onb[(size_t)col * 64 + row] = s;
    }
  }
}

// ---- fallback (tiny ws): R5/R6-validated single-kernel bf16 path ----------
__global__ __launch_bounds__(256)
void gram_fallback_kernel(const float* __restrict__ vin,
                          const float* __restrict__ uf32,
                          float* __restrict__ out)
{
  __shared__ float Red[4][C_DIM][20];

  const int tid = threadIdx.x;
  const int w   = tid >> 6;
  const int l   = tid & 63;
  const int n   = blockIdx.x;
  const int hg  = l >> 5;
  const int lm  = l & 31;
  const int kq  = w * 1024;

  f32x16_t acc[2][2];
#pragma unroll
  for (int a = 0; a < 2; ++a)
#pragma unroll
    for (int c = 0; c < 2; ++c)
#pragma unroll
      for (int i = 0; i < 16; ++i) acc[a][c][i] = 0.0f;

  const char* vg  = (const char*)(vin + (size_t)n * D_DIM + kq) + hg * 32;
  const char* ua  = (const char*)(uf32 + (size_t)lm * D_DIM + kq) + hg * 32;
  const char* ubx = ua + (size_t)32 * D_DIM * 4;
  for (int s = 0; s < 64; ++s) {
    const float4 a0 = *(const float4*)(ua  + (size_t)s * 64);
    const float4 a1 = *(const float4*)(ua  + (size_t)s * 64 + 16);
    const float4 b0 = *(const float4*)(ubx + (size_t)s * 64);
    const float4 b1 = *(const float4*)(ubx + (size_t)s * 64 + 16);
    const float4 va = *(const float4*)(vg + s * 64);
    const float4 vb = *(const float4*)(vg + s * 64 + 16);
    Frag f0, f1, sa0, sa1;
    f0.u[0] = pk_bf16(a0.x, a0.y);  f0.u[1] = pk_bf16(a0.z, a0.w);
    f0.u[2] = pk_bf16(a1.x, a1.y);  f0.u[3] = pk_bf16(a1.z, a1.w);
    f1.u[0] = pk_bf16(b0.x, b0.y);  f1.u[1] = pk_bf16(b0.z, b0.w);
    f1.u[2] = pk_bf16(b1.x, b1.y);  f1.u[3] = pk_bf16(b1.z, b1.w);
    sa0.u[0] = pk_bf16(a0.x * va.x, a0.y * va.y);
    sa0.u[1] = pk_bf16(a0.z * va.z, a0.w * va.w);
    sa0.u[2] = pk_bf16(a1.x * vb.x, a1.y * vb.y);
    sa0.u[3] = pk_bf16(a1.z * vb.z, a1.w * vb.w);
    sa1.u[0] = pk_bf16(b0.x * va.x, b0.y * va.y);
    sa1.u[1] = pk_bf16(b0.z * va.z, b0.w * va.w);
    sa1.u[2] = pk_bf16(b1.x * vb.x, b1.y * vb.y);
    sa1.u[3] = pk_bf16(b1.z * vb.z, b1.w * vb.w);
    acc[0][0] = MFMA32B(sa0.b, f0.b, acc[0][0]);
    acc[0][1] = MFMA32B(sa0.b, f1.b, acc[0][1]);
    acc[1][0] = MFMA32B(sa1.b, f0.b, acc[1][0]);
    acc[1][1] = MFMA32B(sa1.b, f1.b, acc[1][1]);
  }

#pragma unroll
  for (int t = 0; t < 4; ++t) {
    __syncthreads();
    {
      const f32x16_t A = acc[t >> 1][t & 1];
      float* rp = &Red[w][l][0];
#pragma unroll
      for (int qq = 0; qq < 4; ++qq)
        *(float4*)(rp + qq * 4) =
            make_float4(A[qq * 4 + 0], A[qq * 4 + 1], A[qq * 4 + 2], A[qq * 4 + 3]);
    }
    __syncthreads();
    {
      const float4 r0 = *(const float4*)(&Red[0][l][w * 4]);
      const float4 r1 = *(const float4*)(&Red[1][l][w * 4]);
      const float4 r2 = *(const float4*)(&Red[2][l][w * 4]);
      const float4 r3 = *(const float4*)(&Red[3][l][w * 4]);
      const int tr = t >> 1, tc = t & 1;
      const int rbase = tr * 32 + w * 8 + ((l >> 5) << 2);
      const int col   = tc * 32 + (l & 31);
      float* op = out + (size_t)n * 4096 + (size_t)rbase * 64 + col;
      op[0]   = r0.x + r1.x + r2.x + r3.x;
      op[64]  = r0.y + r1.y + r2.y + r3.y;
      op[128] = r0.z + r1.z + r2.z + r3.z;
      op[192] = r0.w + r1.w + r2.w + r3.w;
    }
  }
}

extern "C" void kernel_launch(void* const* d_in, const int* in_sizes, int n_in,
                              void* d_out, int out_size, void* d_ws, size_t ws_size,
                              hipStream_t stream) {
  const float* v   = (const float*)d_in[0];
  const float* u   = (const float*)d_in[1];
  float*       out = (float*)d_out;
  if (ws_size >= ((size_t)4 << 20)) {
    _Float16* uh = (_Float16*)d_ws;
    _Float16* vh = (_Float16*)((char*)d_ws + VH_OFF);
    prep_kernel<<<dim3(640), dim3(256), 0, stream>>>(u, v, uh, vh);
    gram_kernel<<<dim3(N_DIM), dim3(1024), 0, stream>>>(vh, uh, out);
  } else {
    gram_fallback_kernel<<<dim3(N_DIM), dim3(256), 0, stream>>>(v, u, out);
  }
}

// Round 18
// 21.595 us; speedup vs baseline: 1.2268x; 1.2268x over previous
//
#include <hip/hip_runtime.h>
#include <stdint.h>

#define N_DIM 256
#define C_DIM 64
#define D_DIM 4096
#define NWAVE 16              // waves per block (K-split ways, in-block)
#define KWV   (D_DIM / NWAVE) // 256 k per wave
#define NSTEP (KWV / 16)      // 16 MFMA k-steps per wave
#define PDEP  5               // u prefetch pipeline depth

// ws layout: uh (f16 u, 512 KB) @0; vh (f16 v, 2 MB) @1MB
#define VH_OFF   (1u << 20)

typedef __bf16    bf16x8_t __attribute__((ext_vector_type(8)));
typedef _Float16  f16x8_t  __attribute__((ext_vector_type(8)));
typedef float     f32x16_t __attribute__((ext_vector_type(16)));

union Frag {
  uint4     q;
  uint32_t  u[4];
  bf16x8_t  b;
};
union FragH {
  uint4     q;
  _Float16  h[8];
  f16x8_t   v;
};

__device__ __forceinline__ uint32_t pk_bf16(float lo, float hi) {
  uint32_t d;
  asm("v_cvt_pk_bf16_f32 %0, %1, %2" : "=v"(d) : "v"(lo), "v"(hi));
  return d;
}

#define MFMA32H(a, b, c) __builtin_amdgcn_mfma_f32_32x32x16_f16(a, b, c, 0, 0, 0)
#define MFMA32B(a, b, c) __builtin_amdgcn_mfma_f32_32x32x16_bf16(a, b, c, 0, 0, 0)

// ---- prep helpers (R6/R8-validated) ---------------------------------------
__device__ __forceinline__ void prep_u_unit(const float* __restrict__ u,
                                            _Float16* __restrict__ uh, int t) {
  const int row = t >> 9;
  const int k8  = t & 511;
  const float4* p = (const float4*)(u + (size_t)row * D_DIM + (size_t)k8 * 8);
  const float4 a = p[0], b = p[1];
  FragH o;
  o.h[0] = (_Float16)a.x; o.h[1] = (_Float16)a.y;
  o.h[2] = (_Float16)a.z; o.h[3] = (_Float16)a.w;
  o.h[4] = (_Float16)b.x; o.h[5] = (_Float16)b.y;
  o.h[6] = (_Float16)b.z; o.h[7] = (_Float16)b.w;
  *(uint4*)(uh + (size_t)(k8 * C_DIM + row) * 8) = o.q;
}

__device__ __forceinline__ void prep_v_unit(const float* __restrict__ v,
                                            _Float16* __restrict__ vh, int t) {
  const float4* p = (const float4*)(v + (size_t)t * 8);
  const float4 a = p[0], b = p[1];
  FragH o;
  o.h[0] = (_Float16)a.x; o.h[1] = (_Float16)a.y;
  o.h[2] = (_Float16)a.z; o.h[3] = (_Float16)a.w;
  o.h[4] = (_Float16)b.x; o.h[5] = (_Float16)b.y;
  o.h[6] = (_Float16)b.z; o.h[7] = (_Float16)b.w;
  *(uint4*)(vh + (size_t)t * 8) = o.q;
}

__global__ __launch_bounds__(256) void prep_kernel(const float* __restrict__ u,
                                                   const float* __restrict__ v,
                                                   _Float16* __restrict__ uh,
                                                   _Float16* __restrict__ vh) {
  const int gid = blockIdx.x * 256 + threadIdx.x;
  if (blockIdx.x < 128) prep_u_unit(u, uh, gid);
  else                  prep_v_unit(v, vh, gid - 32768);
}

// ---- gram: one 1024-thread block per n; 16-way K-split; symmetric 3-tile --
// R12-validated loop; v served from LDS (DS pipe) to de-serialize the L1 port.
__global__ __launch_bounds__(1024, 4)
void gram_kernel(const _Float16* __restrict__ vh,
                 const _Float16* __restrict__ uh,
                 float* __restrict__ out)
{
  __shared__ float Red[NWAVE][C_DIM][17];   // 69.6 KB; odd stride -> 2/bank (free)
  __shared__ uint4 Lv[512];                 // 8 KB: this n's v slice (f16)

  const int tid = threadIdx.x;
  const int w   = tid >> 6;      // wave id = K-segment (0..15)
  const int l   = tid & 63;
  const int n   = blockIdx.x;
  const int hg  = l >> 5;
  const int lm  = l & 31;

  // stage v slice: 512 threads x 16 B, coalesced global read, plain LDS write
  if (tid < 512)
    Lv[tid] = ((const uint4*)(vh + (size_t)n * D_DIM))[tid];

  f32x16_t acc0, acc1, acc2;     // tiles (0,0), (1,0), (1,1); (0,1)=T(1,0)
#pragma unroll
  for (int i = 0; i < 16; ++i) { acc0[i] = 0.0f; acc1[i] = 0.0f; acc2[i] = 0.0f; }

  // u fragments: validated subtile addressing; k8 base = w*32 + hg
  const char* up = (const char*)uh + ((size_t)(w * 32 + hg)) * 1024 + (size_t)lm * 16;

  // PDEP-deep u pipeline (modular window; full unroll makes indices static)
  FragH pa[PDEP], pb[PDEP];
#pragma unroll
  for (int i = 0; i < PDEP; ++i) {
    pa[i].q = *(const uint4*)(up + i * 2048);
    pb[i].q = *(const uint4*)(up + i * 2048 + 512);
  }
  up += PDEP * 2048;

  __syncthreads();               // v slice visible to all waves
  // per-wave LDS v base: wave's 512 B segment + hg's 16 B half
  const char* lvb = (const char*)Lv + w * 512 + hg * 16;

#pragma unroll
  for (int s = 0; s < NSTEP; ++s) {
    const int cur = s % PDEP;
    FragH vv;
    vv.q = *(const uint4*)(lvb + s * 32);   // ds_read_b128, 2-addr broadcast
    FragH sa0, sa1;
    sa0.v = pa[cur].v * vv.v;     // v_pk_mul_f16
    sa1.v = pb[cur].v * vv.v;
    acc0 = MFMA32H(sa0.v, pa[cur].v, acc0);   // tile (0,0)
    acc1 = MFMA32H(sa1.v, pa[cur].v, acc1);   // tile (1,0)
    acc2 = MFMA32H(sa1.v, pb[cur].v, acc2);   // tile (1,1)
    if (s + PDEP < NSTEP) {       // guarded refill: no tail over-read
      pa[cur].q = *(const uint4*)(up);
      pb[cur].q = *(const uint4*)(up + 512);
      up += 2048;
    }
  }

  // ---- in-block K-reduction (16 partials) + direct out, 3 phases ----------
  // Producer (validated): acc tile (tr,tc) reg j of lane (hg,lm) ->
  //   row = tr*32 + 4*hg + (j&3) + 8*(j>>2), col = tc*32 + lm.
  // Reader (w,l) owns j = w; sums 16 waves. Phase 1 also stores the
  // transposed element into tile (0,1) (gram is symmetric).
  float* onb = out + (size_t)n * 4096;
#pragma unroll
  for (int p = 0; p < 3; ++p) {
    const int tr = (p >= 1) ? 1 : 0;
    const int tc = (p == 2) ? 1 : 0;
    __syncthreads();                 // Red free for reuse
    {
      const f32x16_t A = (p == 0) ? acc0 : (p == 1) ? acc1 : acc2;
      float* rp = &Red[w][l][0];
#pragma unroll
      for (int j = 0; j < 16; ++j)
        rp[j] = A[j];
    }
    __syncthreads();                 // all partials visible
    {
      float s = 0.0f;
#pragma unroll
      for (int ww = 0; ww < NWAVE; ++ww)
        s += Red[ww][l][w];
      const int row = tr * 32 + 4 * hg + (w & 3) + 8 * (w >> 2);
      const int col = tc * 32 + lm;
      onb[(size_t)row * 64 + col] = s;
      if (p == 1)                    // mirror into tile (0,1)
        onb[(size_t)col * 64 + row] = s;
    }
  }
}

// ---- fallback (tiny ws): R5/R6-validated single-kernel bf16 path ----------
__global__ __launch_bounds__(256)
void gram_fallback_kernel(const float* __restrict__ vin,
                          const float* __restrict__ uf32,
                          float* __restrict__ out)
{
  __shared__ float Red[4][C_DIM][20];

  const int tid = threadIdx.x;
  const int w   = tid >> 6;
  const int l   = tid & 63;
  const int n   = blockIdx.x;
  const int hg  = l >> 5;
  const int lm  = l & 31;
  const int kq  = w * 1024;

  f32x16_t acc[2][2];
#pragma unroll
  for (int a = 0; a < 2; ++a)
#pragma unroll
    for (int c = 0; c < 2; ++c)
#pragma unroll
      for (int i = 0; i < 16; ++i) acc[a][c][i] = 0.0f;

  const char* vg  = (const char*)(vin + (size_t)n * D_DIM + kq) + hg * 32;
  const char* ua  = (const char*)(uf32 + (size_t)lm * D_DIM + kq) + hg * 32;
  const char* ubx = ua + (size_t)32 * D_DIM * 4;
  for (int s = 0; s < 64; ++s) {
    const float4 a0 = *(const float4*)(ua  + (size_t)s * 64);
    const float4 a1 = *(const float4*)(ua  + (size_t)s * 64 + 16);
    const float4 b0 = *(const float4*)(ubx + (size_t)s * 64);
    const float4 b1 = *(const float4*)(ubx + (size_t)s * 64 + 16);
    const float4 va = *(const float4*)(vg + s * 64);
    const float4 vb = *(const float4*)(vg + s * 64 + 16);
    Frag f0, f1, sa0, sa1;
    f0.u[0] = pk_bf16(a0.x, a0.y);  f0.u[1] = pk_bf16(a0.z, a0.w);
    f0.u[2] = pk_bf16(a1.x, a1.y);  f0.u[3] = pk_bf16(a1.z, a1.w);
    f1.u[0] = pk_bf16(b0.x, b0.y);  f1.u[1] = pk_bf16(b0.z, b0.w);
    f1.u[2] = pk_bf16(b1.x, b1.y);  f1.u[3] = pk_bf16(b1.z, b1.w);
    sa0.u[0] = pk_bf16(a0.x * va.x, a0.y * va.y);
    sa0.u[1] = pk_bf16(a0.z * va.z, a0.w * va.w);
    sa0.u[2] = pk_bf16(a1.x * vb.x, a1.y * vb.y);
    sa0.u[3] = pk_bf16(a1.z * vb.z, a1.w * vb.w);
    sa1.u[0] = pk_bf16(b0.x * va.x, b0.y * va.y);
    sa1.u[1] = pk_bf16(b0.z * va.z, b0.w * va.w);
    sa1.u[2] = pk_bf16(b1.x * vb.x, b1.y * vb.y);
    sa1.u[3] = pk_bf16(b1.z * vb.z, b1.w * vb.w);
    acc[0][0] = MFMA32B(sa0.b, f0.b, acc[0][0]);
    acc[0][1] = MFMA32B(sa0.b, f1.b, acc[0][1]);
    acc[1][0] = MFMA32B(sa1.b, f0.b, acc[1][0]);
    acc[1][1] = MFMA32B(sa1.b, f1.b, acc[1][1]);
  }

#pragma unroll
  for (int t = 0; t < 4; ++t) {
    __syncthreads();
    {
      const f32x16_t A = acc[t >> 1][t & 1];
      float* rp = &Red[w][l][0];
#pragma unroll
      for (int qq = 0; qq < 4; ++qq)
        *(float4*)(rp + qq * 4) =
            make_float4(A[qq * 4 + 0], A[qq * 4 + 1], A[qq * 4 + 2], A[qq * 4 + 3]);
    }
    __syncthreads();
    {
      const float4 r0 = *(const float4*)(&Red[0][l][w * 4]);
      const float4 r1 = *(const float4*)(&Red[1][l][w * 4]);
      const float4 r2 = *(const float4*)(&Red[2][l][w * 4]);
      const float4 r3 = *(const float4*)(&Red[3][l][w * 4]);
      const int tr = t >> 1, tc = t & 1;
      const int rbase = tr * 32 + w * 8 + ((l >> 5) << 2);
      const int col   = tc * 32 + (l & 31);
      float* op = out + (size_t)n * 4096 + (size_t)rbase * 64 + col;
      op[0]   = r0.x + r1.x + r2.x + r3.x;
      op[64]  = r0.y + r1.y + r2.y + r3.y;
      op[128] = r0.z + r1.z + r2.z + r3.z;
      op[192] = r0.w + r1.w + r2.w + r3.w;
    }
  }
}

extern "C" void kernel_launch(void* const* d_in, const int* in_sizes, int n_in,
                              void* d_out, int out_size, void* d_ws, size_t ws_size,
                              hipStream_t stream) {
  const float* v   = (const float*)d_in[0];
  const float* u   = (const float*)d_in[1];
  float*       out = (float*)d_out;
  if (ws_size >= ((size_t)4 << 20)) {
    _Float16* uh = (_Float16*)d_ws;
    _Float16* vh = (_Float16*)((char*)d_ws + VH_OFF);
    prep_kernel<<<dim3(640), dim3(256), 0, stream>>>(u, v, uh, vh);
    gram_kernel<<<dim3(N_DIM), dim3(1024), 0, stream>>>(vh, uh, out);
  } else {
    gram_fallback_kernel<<<dim3(N_DIM), dim3(256), 0, stream>>>(v, u, out);
  }
}

// Round 19
// 21.343 us; speedup vs baseline: 1.2413x; 1.0118x over previous
//
#include <hip/hip_runtime.h>
#include <stdint.h>

#define N_DIM 256
#define C_DIM 64
#define D_DIM 4096
#define NWAVE 16              // waves per block (K-split ways, in-block)
#define KWV   (D_DIM / NWAVE) // 256 k per wave
#define NSTEP (KWV / 16)      // 16 MFMA k-steps per wave
#define PDEP  5               // u prefetch pipeline depth

// ws layout: uh (f16 u, 512 KB) @0; vh (f16 v, 2 MB) @1MB
#define VH_OFF   (1u << 20)

typedef __bf16    bf16x8_t __attribute__((ext_vector_type(8)));
typedef _Float16  f16x8_t  __attribute__((ext_vector_type(8)));
typedef float     f32x16_t __attribute__((ext_vector_type(16)));

union Frag {
  uint4     q;
  uint32_t  u[4];
  bf16x8_t  b;
};
union FragH {
  uint4     q;
  _Float16  h[8];
  f16x8_t   v;
};

__device__ __forceinline__ uint32_t pk_bf16(float lo, float hi) {
  uint32_t d;
  asm("v_cvt_pk_bf16_f32 %0, %1, %2" : "=v"(d) : "v"(lo), "v"(hi));
  return d;
}

#define MFMA32H(a, b, c) __builtin_amdgcn_mfma_f32_32x32x16_f16(a, b, c, 0, 0, 0)
#define MFMA32B(a, b, c) __builtin_amdgcn_mfma_f32_32x32x16_bf16(a, b, c, 0, 0, 0)

// ---- prep helpers (R6/R8-validated) ---------------------------------------
__device__ __forceinline__ void prep_u_unit(const float* __restrict__ u,
                                            _Float16* __restrict__ uh, int t) {
  const int row = t >> 9;
  const int k8  = t & 511;
  const float4* p = (const float4*)(u + (size_t)row * D_DIM + (size_t)k8 * 8);
  const float4 a = p[0], b = p[1];
  FragH o;
  o.h[0] = (_Float16)a.x; o.h[1] = (_Float16)a.y;
  o.h[2] = (_Float16)a.z; o.h[3] = (_Float16)a.w;
  o.h[4] = (_Float16)b.x; o.h[5] = (_Float16)b.y;
  o.h[6] = (_Float16)b.z; o.h[7] = (_Float16)b.w;
  *(uint4*)(uh + (size_t)(k8 * C_DIM + row) * 8) = o.q;
}

__device__ __forceinline__ void prep_v_unit(const float* __restrict__ v,
                                            _Float16* __restrict__ vh, int t) {
  const float4* p = (const float4*)(v + (size_t)t * 8);
  const float4 a = p[0], b = p[1];
  FragH o;
  o.h[0] = (_Float16)a.x; o.h[1] = (_Float16)a.y;
  o.h[2] = (_Float16)a.z; o.h[3] = (_Float16)a.w;
  o.h[4] = (_Float16)b.x; o.h[5] = (_Float16)b.y;
  o.h[6] = (_Float16)b.z; o.h[7] = (_Float16)b.w;
  *(uint4*)(vh + (size_t)t * 8) = o.q;
}

__global__ __launch_bounds__(256) void prep_kernel(const float* __restrict__ u,
                                                   const float* __restrict__ v,
                                                   _Float16* __restrict__ uh,
                                                   _Float16* __restrict__ vh) {
  const int gid = blockIdx.x * 256 + threadIdx.x;
  if (blockIdx.x < 128) prep_u_unit(u, uh, gid);
  else                  prep_v_unit(v, vh, gid - 32768);
}

// ---- gram: one 1024-thread block per n; 16-way K-split; symmetric 3-tile --
// R18-validated loop; 2-phase / 3-barrier epilogue with coalesced mirror.
__global__ __launch_bounds__(1024, 4)
void gram_kernel(const _Float16* __restrict__ vh,
                 const _Float16* __restrict__ uh,
                 float* __restrict__ out)
{
  __shared__ float Red[2][NWAVE][C_DIM][17]; // 136 KB; stride 17 -> conflict-free
  __shared__ uint4 Lv[512];                  // 8 KB: this n's v slice (f16)

  const int tid = threadIdx.x;
  const int w   = tid >> 6;      // wave id = K-segment (0..15)
  const int l   = tid & 63;
  const int n   = blockIdx.x;
  const int hg  = l >> 5;
  const int lm  = l & 31;

  // stage v slice: 512 threads x 16 B, coalesced global read, plain LDS write
  if (tid < 512)
    Lv[tid] = ((const uint4*)(vh + (size_t)n * D_DIM))[tid];

  f32x16_t acc0, acc1, acc2;     // tiles (0,0), (1,0), (1,1); (0,1)=T(1,0)
#pragma unroll
  for (int i = 0; i < 16; ++i) { acc0[i] = 0.0f; acc1[i] = 0.0f; acc2[i] = 0.0f; }

  // u fragments: validated subtile addressing; k8 base = w*32 + hg
  const char* up = (const char*)uh + ((size_t)(w * 32 + hg)) * 1024 + (size_t)lm * 16;

  // PDEP-deep u pipeline (modular window; full unroll makes indices static)
  FragH pa[PDEP], pb[PDEP];
#pragma unroll
  for (int i = 0; i < PDEP; ++i) {
    pa[i].q = *(const uint4*)(up + i * 2048);
    pb[i].q = *(const uint4*)(up + i * 2048 + 512);
  }
  up += PDEP * 2048;

  __syncthreads();               // v slice visible to all waves
  // per-wave LDS v base: wave's 512 B segment + hg's 16 B half
  const char* lvb = (const char*)Lv + w * 512 + hg * 16;

#pragma unroll
  for (int s = 0; s < NSTEP; ++s) {
    const int cur = s % PDEP;
    FragH vv;
    vv.q = *(const uint4*)(lvb + s * 32);   // ds_read_b128, 2-addr broadcast
    FragH sa0, sa1;
    sa0.v = pa[cur].v * vv.v;     // v_pk_mul_f16
    sa1.v = pb[cur].v * vv.v;
    acc0 = MFMA32H(sa0.v, pa[cur].v, acc0);   // tile (0,0)
    acc1 = MFMA32H(sa1.v, pa[cur].v, acc1);   // tile (1,0)
    acc2 = MFMA32H(sa1.v, pb[cur].v, acc2);   // tile (1,1)
    if (s + PDEP < NSTEP) {       // guarded refill: no tail over-read
      pa[cur].q = *(const uint4*)(up);
      pb[cur].q = *(const uint4*)(up + 512);
      up += 2048;
    }
  }

  // ---- epilogue: 2 phases, 3 barriers, coalesced mirror -------------------
  // Producer (validated): acc tile reg j of lane (hg,lm) -> local
  //   row = 4*hg + (j&3) + 8*(j>>2) (0..31), col = lm; tile offsets added below.
  // Reader (w,l) owns j = w; sums 16 waves.
  float* onb = out + (size_t)n * 4096;
  {
    // phase A writes: tile00 -> Red[0], tile10 -> Red[1]
    float* rp0 = &Red[0][w][l][0];
    float* rp1 = &Red[1][w][l][0];
#pragma unroll
    for (int j = 0; j < 16; ++j) { rp0[j] = acc0[j]; rp1[j] = acc1[j]; }
    __syncthreads();
    // phase A reads
    float s0 = 0.0f, s1 = 0.0f;
#pragma unroll
    for (int ww = 0; ww < NWAVE; ++ww) {
      s0 += Red[0][ww][l][w];
      s1 += Red[1][ww][l][w];
    }
    const int row = 4 * hg + (w & 3) + 8 * (w >> 2);
    onb[(size_t)row * 64 + lm]        = s0;   // tile (0,0)
    onb[(size_t)(32 + row) * 64 + lm] = s1;   // tile (1,0)
    // coalesced tile (0,1) mirror: tile01(r01,c01) = tile10(c01,r01).
    // thread (w,l): c01 = lm (coalesced), r01 = 2w + hg;
    //   source partials: lane = ((c01>>2)&1)*32 + r01, reg j = (c01&3)|((c01>>3)<<2)
    const int jj   = (lm & 3) | ((lm >> 3) << 2);
    const int srcl = ((lm >> 2) & 1) * 32 + 2 * w + hg;
    float s01 = 0.0f;
#pragma unroll
    for (int ww = 0; ww < NWAVE; ++ww)
      s01 += Red[1][ww][srcl][jj];
    onb[(size_t)(2 * w + hg) * 64 + 32 + lm] = s01;
    __syncthreads();                 // all phase-A reads done; Red[0] reusable
    // phase B: tile11 via Red[0]
    float* rp2 = &Red[0][w][l][0];
#pragma unroll
    for (int j = 0; j < 16; ++j) rp2[j] = acc2[j];
    __syncthreads();
    float s2 = 0.0f;
#pragma unroll
    for (int ww = 0; ww < NWAVE; ++ww)
      s2 += Red[0][ww][l][w];
    onb[(size_t)(32 + row) * 64 + 32 + lm] = s2;  // tile (1,1)
  }
}

// ---- fallback (tiny ws): R5/R6-validated single-kernel bf16 path ----------
__global__ __launch_bounds__(256)
void gram_fallback_kernel(const float* __restrict__ vin,
                          const float* __restrict__ uf32,
                          float* __restrict__ out)
{
  __shared__ float Red[4][C_DIM][20];

  const int tid = threadIdx.x;
  const int w   = tid >> 6;
  const int l   = tid & 63;
  const int n   = blockIdx.x;
  const int hg  = l >> 5;
  const int lm  = l & 31;
  const int kq  = w * 1024;

  f32x16_t acc[2][2];
#pragma unroll
  for (int a = 0; a < 2; ++a)
#pragma unroll
    for (int c = 0; c < 2; ++c)
#pragma unroll
      for (int i = 0; i < 16; ++i) acc[a][c][i] = 0.0f;

  const char* vg  = (const char*)(vin + (size_t)n * D_DIM + kq) + hg * 32;
  const char* ua  = (const char*)(uf32 + (size_t)lm * D_DIM + kq) + hg * 32;
  const char* ubx = ua + (size_t)32 * D_DIM * 4;
  for (int s = 0; s < 64; ++s) {
    const float4 a0 = *(const float4*)(ua  + (size_t)s * 64);
    const float4 a1 = *(const float4*)(ua  + (size_t)s * 64 + 16);
    const float4 b0 = *(const float4*)(ubx + (size_t)s * 64);
    const float4 b1 = *(const float4*)(ubx + (size_t)s * 64 + 16);
    const float4 va = *(const float4*)(vg + s * 64);
    const float4 vb = *(const float4*)(vg + s * 64 + 16);
    Frag f0, f1, sa0, sa1;
    f0.u[0] = pk_bf16(a0.x, a0.y);  f0.u[1] = pk_bf16(a0.z, a0.w);
    f0.u[2] = pk_bf16(a1.x, a1.y);  f0.u[3] = pk_bf16(a1.z, a1.w);
    f1.u[0] = pk_bf16(b0.x, b0.y);  f1.u[1] = pk_bf16(b0.z, b0.w);
    f1.u[2] = pk_bf16(b1.x, b1.y);  f1.u[3] = pk_bf16(b1.z, b1.w);
    sa0.u[0] = pk_bf16(a0.x * va.x, a0.y * va.y);
    sa0.u[1] = pk_bf16(a0.z * va.z, a0.w * va.w);
    sa0.u[2] = pk_bf16(a1.x * vb.x, a1.y * vb.y);
    sa0.u[3] = pk_bf16(a1.z * vb.z, a1.w * vb.w);
    sa1.u[0] = pk_bf16(b0.x * va.x, b0.y * va.y);
    sa1.u[1] = pk_bf16(b0.z * va.z, b0.w * va.w);
    sa1.u[2] = pk_bf16(b1.x * vb.x, b1.y * vb.y);
    sa1.u[3] = pk_bf16(b1.z * vb.z, b1.w * vb.w);
    acc[0][0] = MFMA32B(sa0.b, f0.b, acc[0][0]);
    acc[0][1] = MFMA32B(sa0.b, f1.b, acc[0][1]);
    acc[1][0] = MFMA32B(sa1.b, f0.b, acc[1][0]);
    acc[1][1] = MFMA32B(sa1.b, f1.b, acc[1][1]);
  }

#pragma unroll
  for (int t = 0; t < 4; ++t) {
    __syncthreads();
    {
      const f32x16_t A = acc[t >> 1][t & 1];
      float* rp = &Red[w][l][0];
#pragma unroll
      for (int qq = 0; qq < 4; ++qq)
        *(float4*)(rp + qq * 4) =
            make_float4(A[qq * 4 + 0], A[qq * 4 + 1], A[qq * 4 + 2], A[qq * 4 + 3]);
    }
    __syncthreads();
    {
      const float4 r0 = *(const float4*)(&Red[0][l][w * 4]);
      const float4 r1 = *(const float4*)(&Red[1][l][w * 4]);
      const float4 r2 = *(const float4*)(&Red[2][l][w * 4]);
      const float4 r3 = *(const float4*)(&Red[3][l][w * 4]);
      const int tr = t >> 1, tc = t & 1;
      const int rbase = tr * 32 + w * 8 + ((l >> 5) << 2);
      const int col   = tc * 32 + (l & 31);
      float* op = out + (size_t)n * 4096 + (size_t)rbase * 64 + col;
      op[0]   = r0.x + r1.x + r2.x + r3.x;
      op[64]  = r0.y + r1.y + r2.y + r3.y;
      op[128] = r0.z + r1.z + r2.z + r3.z;
      op[192] = r0.w + r1.w + r2.w + r3.w;
    }
  }
}

extern "C" void kernel_launch(void* const* d_in, const int* in_sizes, int n_in,
                              void* d_out, int out_size, void* d_ws, size_t ws_size,
                              hipStream_t stream) {
  const float* v   = (const float*)d_in[0];
  const float* u   = (const float*)d_in[1];
  float*       out = (float*)d_out;
  if (ws_size >= ((size_t)4 << 20)) {
    _Float16* uh = (_Float16*)d_ws;
    _Float16* vh = (_Float16*)((char*)d_ws + VH_OFF);
    prep_kernel<<<dim3(640), dim3(256), 0, stream>>>(u, v, uh, vh);
    gram_kernel<<<dim3(N_DIM), dim3(1024), 0, stream>>>(vh, uh, out);
  } else {
    gram_fallback_kernel<<<dim3(N_DIM), dim3(256), 0, stream>>>(v, u, out);
  }
}